// Round 15
// baseline (426.227 us; speedup 1.0000x reference)
//
#include <hip/hip_runtime.h>
#include <stdint.h>

// N=16, M=4, D=32, K=256, H=64, W=64 ; P = 262144 pixels
// outputs (concat, read back as f32): sample (P*256), code (P, as float), logit (P*256)
// R15: SINGLE kernel. thread = pixel, full 256-k scan. Codebook rows are
// wave-uniform -> s_load into SGPRs, 2-row ping-pong pipeline (scalar pipe;
// no LDS row reads, no VGPR pressure). Argmax: fast-scan + top-3 margin
// certification + exact-candidate resolve (validated R10-R14 logic).

#define TINY_F 1.17549435082228750797e-38f
#define LN2F   0.69314718055994530942f
#define MARGIN 2.0e-4f

constexpr int KK = 256;
constexpr int DD = 32;

// XLA:CPU vectorized log (GenerateVF32Log / Eigen plog), UNFUSED mul+add.
// Bit-exactness validated round 2 (code absmax == 0). Exact path only.
__device__ __forceinline__ float plog_xla(float xin) {
  #pragma clang fp contract(off)
  uint32_t ix = __float_as_uint(xin);
  int e_i = (int)(ix >> 23) - 126;
  float x = __uint_as_float((ix & 0x007FFFFFu) | 0x3F000000u);
  float e = (float)e_i;
  bool lt = x < 0.707106781186547524f;
  float tmp = lt ? x : 0.0f;
  x = x - 1.0f;
  e = e - (lt ? 1.0f : 0.0f);
  x = x + tmp;
  float z  = x * x;
  float x3 = z * x;
  float y  =  7.0376836292e-2f * x + (-1.1514610310e-1f);
  float y1 = -1.2420140846e-1f * x +   1.4249322787e-1f;
  float y2 =  2.0000714765e-1f * x + (-2.4999993993e-1f);
  y  = y  * x +   1.1676998740e-1f;
  y1 = y1 * x + (-1.6668057665e-1f);
  y2 = y2 * x +   3.3333331174e-1f;
  y  = y * x3 + y1;
  y  = y * x3 + y2;
  y  = y * x3;
  y  = y + e * (-2.12194440e-4f);
  x  = x - 0.5f * z;
  x  = x + y;
  x  = x + e * 0.693359375f;
  return x;
}

__device__ __forceinline__ float sumsq_unfused(const float* v) {
  #pragma clang fp contract(off)
  float a = 0.0f;
  #pragma unroll
  for (int d = 0; d < 32; d++) a = a + v[d] * v[d];
  return a;
}

__device__ __forceinline__ void threefry2x32(uint32_t k0, uint32_t k1,
                                             uint32_t x0, uint32_t x1,
                                             uint32_t& o0, uint32_t& o1) {
  uint32_t ks2 = k0 ^ k1 ^ 0x1BD11BDAu;
  x0 += k0; x1 += k1;
#define TF_RND(r) { x0 += x1; x1 = (x1 << (r)) | (x1 >> (32 - (r))); x1 ^= x0; }
  TF_RND(13) TF_RND(15) TF_RND(26) TF_RND(6)
  x0 += k1; x1 += ks2 + 1u;
  TF_RND(17) TF_RND(29) TF_RND(16) TF_RND(24)
  x0 += ks2; x1 += k0 + 2u;
  TF_RND(13) TF_RND(15) TF_RND(26) TF_RND(6)
  x0 += k0; x1 += k1 + 3u;
  TF_RND(17) TF_RND(29) TF_RND(16) TF_RND(24)
  x0 += k1; x1 += ks2 + 4u;
  TF_RND(13) TF_RND(15) TF_RND(26) TF_RND(6)
  x0 += ks2; x1 += k0 + 5u;
#undef TF_RND
  o0 = x0; o1 = x1;
}

// EXACT gumbel (validated R2). Resolve path only.
__device__ __forceinline__ float gumbel_from_bits(uint32_t bits) {
  uint32_t mant = bits >> 9;
  float f = __uint_as_float(0x3F800000u | mant) - 1.0f;
  float u = mant ? f : TINY_F;
  float t = -plog_xla(u);
  return -plog_xla(t);
}

// FAST gumbel via v_log_f32 (scan only; certified by margin).
__device__ __forceinline__ float gumbel_fast(uint32_t bits) {
  uint32_t mant = bits >> 9;
  float f = __uint_as_float(0x3F800000u | mant) - 1.0f;
  float u = mant ? f : TINY_F;
  float t = -(__log2f(u) * LN2F);
  return -(__log2f(t) * LN2F);
}

#define TRACK(P, KL, BEST, SEC, THI, I1, I2)                                   \
  if ((P) > BEST) { THI = SEC; SEC = BEST; I2 = I1; BEST = (P); I1 = (KL); }   \
  else if ((P) > SEC) { THI = SEC; SEC = (P); I2 = (KL); }                     \
  else if ((P) > THI) THI = (P);

// exact phi for row KI, rows from global (uniform addr -> scalar loads); all
// chains validated (fused ascending inter, unfused x2/c2, plog logit+gumbel).
#define EXACT_PHI_G(OUT, KI)                                                   \
  {                                                                            \
    const int _ki = (KI);                                                      \
    const float* _rp = cbm + (size_t)_ki * DD;                                 \
    float _in = 0.0f;                                                          \
    _Pragma("unroll")                                                          \
    for (int _d = 0; _d < 32; _d++)                                            \
      _in = __builtin_fmaf(xv[_d], _rp[_d], _in);                              \
    float _dd = (x2 + s_c2[_ki]) - 2.0f * _in;                                 \
    float _L = plog_xla(_dd);                                                  \
    uint32_t _v0, _v1;                                                         \
    threefry2x32(0u, 42u, 0u, lbase | (uint32_t)_ki, _v0, _v1);                \
    OUT = gumbel_from_bits(_v0 ^ _v1) + _L;                                    \
  }

// load row KIDX (mod 256) into named buffer (uniform addr -> s_load)
#define LOADROW(DST, KIDX)                                                     \
  {                                                                            \
    const float* _lp = cbm + (size_t)((KIDX) & 255) * DD;                      \
    _Pragma("unroll")                                                          \
    for (int _i = 0; _i < 32; _i++) DST[_i] = _lp[_i];                         \
  }

// compute row KIDX from CUR while issuing load of KIDX+1 into NXT
#define KSG(KIDX, CUR, NXT, LOUT)                                              \
  {                                                                            \
    LOADROW(NXT, (KIDX) + 1)                                                   \
    const float c2k = s_c2[(KIDX)];                                            \
    float in_ = 0.0f;                                                          \
    _Pragma("unroll")                                                          \
    for (int _d = 0; _d < 32; _d++)                                            \
      in_ = __builtin_fmaf(xv[_d], CUR[_d], in_);                              \
    float dd = (x2 + c2k) - 2.0f * in_;                                        \
    LOUT = __log2f(dd) * LN2F;                                                 \
    uint32_t v0_, v1_;                                                         \
    threefry2x32(0u, 42u, 0u, lbase | (uint32_t)(KIDX), v0_, v1_);             \
    float p_ = gumbel_fast(v0_ ^ v1_) + LOUT;                                  \
    TRACK(p_, (KIDX), best, sec, thi, bi1, bi2)                                \
  }

__global__ __launch_bounds__(256, 4)
void mcq_one(const float* __restrict__ x, const float* __restrict__ cb,
             float* __restrict__ sample, float* __restrict__ code,
             float* __restrict__ logit) {
  __shared__ __align__(16) float s_c2[KK];   // 1 KB

  const int t  = threadIdx.x;
  const int gp = (blockIdx.x << 8) + t;      // 1024 blocks x 256 px
  const int nm = gp >> 12;                   // uniform per block (256 | 4096)
  const int m  = nm & 3;
  const int hw = gp & 4095;

  const float* cbm = cb + (size_t)m * (KK * DD);

  // c2 for row t, cooperative (validated unfused chain)
  {
    const float4* rp = (const float4*)(cbm + t * DD);
    float cr[DD];
    #pragma unroll
    for (int j = 0; j < 8; j++) {
      float4 q = rp[j];
      cr[4*j+0] = q.x; cr[4*j+1] = q.y; cr[4*j+2] = q.z; cr[4*j+3] = q.w;
    }
    s_c2[t] = sumsq_unfused(cr);
  }

  // x[d] -> VGPRs (coalesced across threads per d)
  const float* xb = x + (size_t)nm * 131072;
  float xv[DD];
  #pragma unroll
  for (int d = 0; d < DD; d++) xv[d] = xb[(size_t)d * 4096 + hw];
  const float x2 = sumsq_unfused(xv);

  __syncthreads();

  float* lrow = logit + ((size_t)gp << 8);
  const uint32_t lbase = (uint32_t)gp << 8;

  float best = -__builtin_inff(), sec = -__builtin_inff(), thi = -__builtin_inff();
  int bi1 = 0, bi2 = 0;

  float ca[DD], cnb[DD];        // ping-pong row buffers (uniform -> SGPRs)
  LOADROW(ca, 0)

  #pragma unroll 1
  for (int kc = 0; kc < KK; kc += 8) {
    float L0, L1, L2, L3, L4, L5, L6, L7;   // named regs only
    KSG(kc + 0, ca,  cnb, L0)
    KSG(kc + 1, cnb, ca,  L1)
    KSG(kc + 2, ca,  cnb, L2)
    KSG(kc + 3, cnb, ca,  L3)
    KSG(kc + 4, ca,  cnb, L4)
    KSG(kc + 5, cnb, ca,  L5)
    KSG(kc + 6, ca,  cnb, L6)
    KSG(kc + 7, cnb, ca,  L7)               // loads kc+8 -> ca (invariant)
    float4* dst = (float4*)(lrow + kc);     // 32B bursts, own-row contiguous
    dst[0] = make_float4(L0, L1, L2, L3);
    dst[1] = make_float4(L4, L5, L6, L7);
  }

  // resolve winner (validated top-3 margin logic; exact chains)
  int w;
  if (best - sec > MARGIN) {
    w = bi1;
  } else if (best - thi > MARGIN) {
    int ka = bi1 < bi2 ? bi1 : bi2;
    int kb = bi1 < bi2 ? bi2 : bi1;
    float fa, fb;
    EXACT_PHI_G(fa, ka)
    EXACT_PHI_G(fb, kb)
    w = (fb > fa) ? kb : ka;               // tie -> smaller k (first occurrence)
  } else {
    // ultra-rare: full exact rescan
    float bb = -__builtin_inff(); int wbb = 0;
    for (int k2 = 0; k2 < KK; k2++) {
      float ph;
      EXACT_PHI_G(ph, k2)
      if (ph > bb) { bb = ph; wbb = k2; }
    }
    w = wbb;
  }

  code[gp] = (float)w;

  // sample one-hot: 1 KB contiguous per thread (full-line coverage)
  float* srow = sample + ((size_t)gp << 8);
  #pragma unroll
  for (int kq = 0; kq < 64; kq++) {
    const int k0 = kq << 2;
    ((float4*)srow)[kq] = make_float4(
        (w == k0 + 0) ? 1.0f : 0.0f,
        (w == k0 + 1) ? 1.0f : 0.0f,
        (w == k0 + 2) ? 1.0f : 0.0f,
        (w == k0 + 3) ? 1.0f : 0.0f);
  }
}

extern "C" void kernel_launch(void* const* d_in, const int* in_sizes, int n_in,
                              void* d_out, int out_size, void* d_ws, size_t ws_size,
                              hipStream_t stream) {
  const float* x  = (const float*)d_in[0];
  const float* cb = (const float*)d_in[1];

  float* out_f  = (float*)d_out;
  float* sample = out_f;                       // 67108864
  float* code   = out_f + 67108864;            // 262144 (as float)
  float* logit  = out_f + 67108864 + 262144;   // 67108864

  mcq_one<<<1024, 256, 0, stream>>>(x, cb, sample, code, logit);
}

// Round 16
// 385.003 us; speedup vs baseline: 1.1071x; 1.1071x over previous
//
#include <hip/hip_runtime.h>
#include <stdint.h>

// N=16, M=4, D=32, K=256, H=64, W=64 ; P = 262144 pixels
// outputs (concat, read back as f32): sample (P*256), code (P, as float), logit (P*256)
// R16: SINGLE kernel, thread = pixel, full 256-k scan. Codebook rows read
// directly from GLOBAL with wave-uniform addresses (cb is 32KB/m -> L1-hot;
// one 64B line per uniform dwordx4 serves the whole wave). No LDS staging,
// no k-split, no combine kernel. Sample written block-cooperatively
// (full-line). Logit in 64B bursts. Validated arithmetic throughout.

#define TINY_F 1.17549435082228750797e-38f
#define LN2F   0.69314718055994530942f
#define MARGIN 2.0e-4f

constexpr int KK = 256;
constexpr int DD = 32;

// XLA:CPU vectorized log (GenerateVF32Log / Eigen plog), UNFUSED mul+add.
// Bit-exactness validated round 2 (code absmax == 0). Exact path only.
__device__ __forceinline__ float plog_xla(float xin) {
  #pragma clang fp contract(off)
  uint32_t ix = __float_as_uint(xin);
  int e_i = (int)(ix >> 23) - 126;
  float x = __uint_as_float((ix & 0x007FFFFFu) | 0x3F000000u);
  float e = (float)e_i;
  bool lt = x < 0.707106781186547524f;
  float tmp = lt ? x : 0.0f;
  x = x - 1.0f;
  e = e - (lt ? 1.0f : 0.0f);
  x = x + tmp;
  float z  = x * x;
  float x3 = z * x;
  float y  =  7.0376836292e-2f * x + (-1.1514610310e-1f);
  float y1 = -1.2420140846e-1f * x +   1.4249322787e-1f;
  float y2 =  2.0000714765e-1f * x + (-2.4999993993e-1f);
  y  = y  * x +   1.1676998740e-1f;
  y1 = y1 * x + (-1.6668057665e-1f);
  y2 = y2 * x +   3.3333331174e-1f;
  y  = y * x3 + y1;
  y  = y * x3 + y2;
  y  = y * x3;
  y  = y + e * (-2.12194440e-4f);
  x  = x - 0.5f * z;
  x  = x + y;
  x  = x + e * 0.693359375f;
  return x;
}

__device__ __forceinline__ float sumsq_unfused(const float* v) {
  #pragma clang fp contract(off)
  float a = 0.0f;
  #pragma unroll
  for (int d = 0; d < 32; d++) a = a + v[d] * v[d];
  return a;
}

__device__ __forceinline__ void threefry2x32(uint32_t k0, uint32_t k1,
                                             uint32_t x0, uint32_t x1,
                                             uint32_t& o0, uint32_t& o1) {
  uint32_t ks2 = k0 ^ k1 ^ 0x1BD11BDAu;
  x0 += k0; x1 += k1;
#define TF_RND(r) { x0 += x1; x1 = (x1 << (r)) | (x1 >> (32 - (r))); x1 ^= x0; }
  TF_RND(13) TF_RND(15) TF_RND(26) TF_RND(6)
  x0 += k1; x1 += ks2 + 1u;
  TF_RND(17) TF_RND(29) TF_RND(16) TF_RND(24)
  x0 += ks2; x1 += k0 + 2u;
  TF_RND(13) TF_RND(15) TF_RND(26) TF_RND(6)
  x0 += k0; x1 += k1 + 3u;
  TF_RND(17) TF_RND(29) TF_RND(16) TF_RND(24)
  x0 += k1; x1 += ks2 + 4u;
  TF_RND(13) TF_RND(15) TF_RND(26) TF_RND(6)
  x0 += ks2; x1 += k0 + 5u;
#undef TF_RND
  o0 = x0; o1 = x1;
}

// EXACT gumbel (validated R2). Resolve path only.
__device__ __forceinline__ float gumbel_from_bits(uint32_t bits) {
  uint32_t mant = bits >> 9;
  float f = __uint_as_float(0x3F800000u | mant) - 1.0f;
  float u = mant ? f : TINY_F;
  float t = -plog_xla(u);
  return -plog_xla(t);
}

// FAST gumbel via v_log_f32 (scan only; certified by margin).
__device__ __forceinline__ float gumbel_fast(uint32_t bits) {
  uint32_t mant = bits >> 9;
  float f = __uint_as_float(0x3F800000u | mant) - 1.0f;
  float u = mant ? f : TINY_F;
  float t = -(__log2f(u) * LN2F);
  return -(__log2f(t) * LN2F);
}

#define TRACK(P, KL, BEST, SEC, THI, I1, I2)                                   \
  if ((P) > BEST) { THI = SEC; SEC = BEST; I2 = I1; BEST = (P); I1 = (KL); }   \
  else if ((P) > SEC) { THI = SEC; SEC = (P); I2 = (KL); }                     \
  else if ((P) > THI) THI = (P);

// exact phi for row KI (global row, per-thread divergent addr; rare, L1-hot).
#define EXACT_PHI_G(OUT, KI)                                                   \
  {                                                                            \
    const int _ki = (KI);                                                      \
    const float4* _rp = (const float4*)(cbm + (size_t)_ki * DD);               \
    float _in = 0.0f;                                                          \
    _Pragma("unroll")                                                          \
    for (int _j = 0; _j < 8; _j++) {                                           \
      float4 _q = _rp[_j];                                                     \
      _in = __builtin_fmaf(xv[4*_j+0], _q.x, _in);                             \
      _in = __builtin_fmaf(xv[4*_j+1], _q.y, _in);                             \
      _in = __builtin_fmaf(xv[4*_j+2], _q.z, _in);                             \
      _in = __builtin_fmaf(xv[4*_j+3], _q.w, _in);                             \
    }                                                                          \
    float _dd = (x2 + s_c2[_ki]) - 2.0f * _in;                                 \
    float _L = plog_xla(_dd);                                                  \
    uint32_t _v0, _v1;                                                         \
    threefry2x32(0u, 42u, 0u, lbase | (uint32_t)_ki, _v0, _v1);                \
    OUT = gumbel_from_bits(_v0 ^ _v1) + _L;                                    \
  }

// two k per expansion: rows from GLOBAL (uniform addr -> one line/wave/load)
#define K2(KOFF, LA, LB)                                                       \
  {                                                                            \
    const int k0 = kc + (KOFF);                                                \
    const float2 c2p = *(const float2*)(s_c2 + k0);                            \
    const float4* rA = (const float4*)(cbm + (size_t)k0 * DD);                 \
    const float4* rB = rA + 8;                                                 \
    float i0 = 0.0f, i1 = 0.0f;                                                \
    _Pragma("unroll")                                                          \
    for (int j = 0; j < 8; j++) {                                              \
      float4 qa = rA[j], qb = rB[j];                                           \
      i0 = __builtin_fmaf(xv[4*j+0], qa.x, i0);                                \
      i1 = __builtin_fmaf(xv[4*j+0], qb.x, i1);                                \
      i0 = __builtin_fmaf(xv[4*j+1], qa.y, i0);                                \
      i1 = __builtin_fmaf(xv[4*j+1], qb.y, i1);                                \
      i0 = __builtin_fmaf(xv[4*j+2], qa.z, i0);                                \
      i1 = __builtin_fmaf(xv[4*j+2], qb.z, i1);                                \
      i0 = __builtin_fmaf(xv[4*j+3], qa.w, i0);                                \
      i1 = __builtin_fmaf(xv[4*j+3], qb.w, i1);                                \
    }                                                                          \
    float d0 = (x2 + c2p.x) - 2.0f * i0;                                       \
    float d1 = (x2 + c2p.y) - 2.0f * i1;                                       \
    LA = __log2f(d0) * LN2F;                                                   \
    LB = __log2f(d1) * LN2F;                                                   \
    uint32_t a0, a1, b0, b1;                                                   \
    threefry2x32(0u, 42u, 0u, lbase | (uint32_t)k0,       a0, a1);             \
    threefry2x32(0u, 42u, 0u, lbase | (uint32_t)(k0 + 1), b0, b1);             \
    float pA = gumbel_fast(a0 ^ a1) + LA;                                      \
    float pB = gumbel_fast(b0 ^ b1) + LB;                                      \
    TRACK(pA, k0,     best, sec, thi, bi1, bi2)                                \
    TRACK(pB, k0 + 1, best, sec, thi, bi1, bi2)                                \
  }

__global__ __launch_bounds__(256, 4)
void mcq_one(const float* __restrict__ x, const float* __restrict__ cb,
             float* __restrict__ sample, float* __restrict__ code,
             float* __restrict__ logit) {
  __shared__ __align__(16) float s_c2[KK];   // 1 KB
  __shared__ int s_wb[256];                  // 1 KB

  const int t  = threadIdx.x;
  const int gp = (blockIdx.x << 8) + t;      // 1024 blocks x 256 px
  const int nm = gp >> 12;                   // uniform per block (256 | 4096)
  const int m  = nm & 3;
  const int hw = gp & 4095;

  const float* cbm = cb + (size_t)m * (KK * DD);

  // c2 for row t, cooperative (validated unfused chain); cb rows L1/L2-hot
  {
    const float4* rp = (const float4*)(cbm + t * DD);
    float cr[DD];
    #pragma unroll
    for (int j = 0; j < 8; j++) {
      float4 q = rp[j];
      cr[4*j+0] = q.x; cr[4*j+1] = q.y; cr[4*j+2] = q.z; cr[4*j+3] = q.w;
    }
    s_c2[t] = sumsq_unfused(cr);
  }

  // x[d] -> VGPRs (coalesced across threads per d)
  const float* xb = x + (size_t)nm * 131072;
  float xv[DD];
  #pragma unroll
  for (int d = 0; d < DD; d++) xv[d] = xb[(size_t)d * 4096 + hw];
  const float x2 = sumsq_unfused(xv);

  __syncthreads();

  float* lrow = logit + ((size_t)gp << 8);
  const uint32_t lbase = (uint32_t)gp << 8;

  float best = -__builtin_inff(), sec = -__builtin_inff(), thi = -__builtin_inff();
  int bi1 = 0, bi2 = 0;

  #pragma unroll 1
  for (int kc = 0; kc < KK; kc += 16) {
    float L0,L1,L2,L3,L4,L5,L6,L7,L8,L9,L10,L11,L12,L13,L14,L15;  // named only
    K2(0,  L0,  L1)
    K2(2,  L2,  L3)
    K2(4,  L4,  L5)
    K2(6,  L6,  L7)
    K2(8,  L8,  L9)
    K2(10, L10, L11)
    K2(12, L12, L13)
    K2(14, L14, L15)
    // 64B full-line burst (lrow 1KB-aligned, kc multiple of 16)
    float4* dst = (float4*)(lrow + kc);
    dst[0] = make_float4(L0,  L1,  L2,  L3);
    dst[1] = make_float4(L4,  L5,  L6,  L7);
    dst[2] = make_float4(L8,  L9,  L10, L11);
    dst[3] = make_float4(L12, L13, L14, L15);
  }

  // resolve winner (validated top-3 margin logic; exact chains)
  int w;
  if (best - sec > MARGIN) {
    w = bi1;
  } else if (best - thi > MARGIN) {
    int ka = bi1 < bi2 ? bi1 : bi2;
    int kb = bi1 < bi2 ? bi2 : bi1;
    float fa, fb;
    EXACT_PHI_G(fa, ka)
    EXACT_PHI_G(fb, kb)
    w = (fb > fa) ? kb : ka;               // tie -> smaller k (first occurrence)
  } else {
    // ultra-rare: full exact rescan
    float bb = -__builtin_inff(); int wbb = 0;
    for (int k2 = 0; k2 < KK; k2++) {
      float ph;
      EXACT_PHI_G(ph, k2)
      if (ph > bb) { bb = ph; wbb = k2; }
    }
    w = wbb;
  }

  code[gp] = (float)w;
  s_wb[t] = w;
  __syncthreads();

  // cooperative one-hot sample: each wave-instr writes 1KB contiguous
  const int lane = t & 63, wv = t >> 6;
  const int pbase = blockIdx.x << 8;
  const int k0 = lane << 2;
  for (int r = wv * 64; r < (wv + 1) * 64; r++) {
    const int wr = s_wb[r];
    float4 v;
    v.x = (wr == k0 + 0) ? 1.0f : 0.0f;
    v.y = (wr == k0 + 1) ? 1.0f : 0.0f;
    v.z = (wr == k0 + 2) ? 1.0f : 0.0f;
    v.w = (wr == k0 + 3) ? 1.0f : 0.0f;
    ((float4*)(sample + (((size_t)(pbase + r)) << 8)))[lane] = v;
  }
}

extern "C" void kernel_launch(void* const* d_in, const int* in_sizes, int n_in,
                              void* d_out, int out_size, void* d_ws, size_t ws_size,
                              hipStream_t stream) {
  const float* x  = (const float*)d_in[0];
  const float* cb = (const float*)d_in[1];

  float* out_f  = (float*)d_out;
  float* sample = out_f;                       // 67108864
  float* code   = out_f + 67108864;            // 262144 (as float)
  float* logit  = out_f + 67108864 + 262144;   // 67108864

  mcq_one<<<1024, 256, 0, stream>>>(x, cb, sample, code, logit);
}

// Round 17
// 320.918 us; speedup vs baseline: 1.3281x; 1.1997x over previous
//
#include <hip/hip_runtime.h>
#include <stdint.h>

// N=16, M=4, D=32, K=256, H=64, W=64 ; P = 262144 pixels
// outputs (concat, read back as f32): sample (P*256), code (P, as float), logit (P*256)
// d_ws: uint2[2][P] = (exact phi bits, winner k) per (half, pixel)
// R17 = R10 grid (2048 half-k blocks -> 32 waves/CU, 100% occupancy) +
//       R16 row source (c-rows via wave-uniform GLOBAL loads, L1-hot;
//       LDS holds only c2). DS pipe freed; VALU-bound at full TLP.

#define TINY_F 1.17549435082228750797e-38f
#define LN2F   0.69314718055994530942f
#define MARGIN 2.0e-4f

constexpr int KK   = 256;
constexpr int DD   = 32;
constexpr int HALF = 128;
constexpr int P_TOT = 262144;

// XLA:CPU vectorized log (GenerateVF32Log / Eigen plog), UNFUSED mul+add.
// Bit-exactness validated round 2 (code absmax == 0). Exact path only.
__device__ __forceinline__ float plog_xla(float xin) {
  #pragma clang fp contract(off)
  uint32_t ix = __float_as_uint(xin);
  int e_i = (int)(ix >> 23) - 126;
  float x = __uint_as_float((ix & 0x007FFFFFu) | 0x3F000000u);
  float e = (float)e_i;
  bool lt = x < 0.707106781186547524f;
  float tmp = lt ? x : 0.0f;
  x = x - 1.0f;
  e = e - (lt ? 1.0f : 0.0f);
  x = x + tmp;
  float z  = x * x;
  float x3 = z * x;
  float y  =  7.0376836292e-2f * x + (-1.1514610310e-1f);
  float y1 = -1.2420140846e-1f * x +   1.4249322787e-1f;
  float y2 =  2.0000714765e-1f * x + (-2.4999993993e-1f);
  y  = y  * x +   1.1676998740e-1f;
  y1 = y1 * x + (-1.6668057665e-1f);
  y2 = y2 * x +   3.3333331174e-1f;
  y  = y * x3 + y1;
  y  = y * x3 + y2;
  y  = y * x3;
  y  = y + e * (-2.12194440e-4f);
  x  = x - 0.5f * z;
  x  = x + y;
  x  = x + e * 0.693359375f;
  return x;
}

__device__ __forceinline__ float sumsq_unfused(const float* v) {
  #pragma clang fp contract(off)
  float a = 0.0f;
  #pragma unroll
  for (int d = 0; d < 32; d++) a = a + v[d] * v[d];
  return a;
}

__device__ __forceinline__ void threefry2x32(uint32_t k0, uint32_t k1,
                                             uint32_t x0, uint32_t x1,
                                             uint32_t& o0, uint32_t& o1) {
  uint32_t ks2 = k0 ^ k1 ^ 0x1BD11BDAu;
  x0 += k0; x1 += k1;
#define TF_RND(r) { x0 += x1; x1 = (x1 << (r)) | (x1 >> (32 - (r))); x1 ^= x0; }
  TF_RND(13) TF_RND(15) TF_RND(26) TF_RND(6)
  x0 += k1; x1 += ks2 + 1u;
  TF_RND(17) TF_RND(29) TF_RND(16) TF_RND(24)
  x0 += ks2; x1 += k0 + 2u;
  TF_RND(13) TF_RND(15) TF_RND(26) TF_RND(6)
  x0 += k0; x1 += k1 + 3u;
  TF_RND(17) TF_RND(29) TF_RND(16) TF_RND(24)
  x0 += k1; x1 += ks2 + 4u;
  TF_RND(13) TF_RND(15) TF_RND(26) TF_RND(6)
  x0 += ks2; x1 += k0 + 5u;
#undef TF_RND
  o0 = x0; o1 = x1;
}

// EXACT gumbel (validated R2).
__device__ __forceinline__ float gumbel_from_bits(uint32_t bits) {
  uint32_t mant = bits >> 9;
  float f = __uint_as_float(0x3F800000u | mant) - 1.0f;
  float u = mant ? f : TINY_F;
  float t = -plog_xla(u);
  return -plog_xla(t);
}

// FAST gumbel via v_log_f32 (scan only; certified by margin).
__device__ __forceinline__ float gumbel_fast(uint32_t bits) {
  uint32_t mant = bits >> 9;
  float f = __uint_as_float(0x3F800000u | mant) - 1.0f;
  float u = mant ? f : TINY_F;
  float t = -(__log2f(u) * LN2F);
  return -(__log2f(t) * LN2F);
}

#define TRACK(P, KL, BEST, SEC, THI, I1, I2)                                   \
  if ((P) > BEST) { THI = SEC; SEC = BEST; I2 = I1; BEST = (P); I1 = (KL); }   \
  else if ((P) > SEC) { THI = SEC; SEC = (P); I2 = (KL); }                     \
  else if ((P) > THI) THI = (P);

// exact phi for local row KL (global row, per-lane addr; rare path, L1-hot)
#define EXACT_PHI(OUT, KL)                                                     \
  {                                                                            \
    const int _kl = (KL);                                                      \
    const float4* _rp = (const float4*)(cbm + (size_t)_kl * DD);               \
    float _in = 0.0f;                                                          \
    _Pragma("unroll")                                                          \
    for (int _j = 0; _j < 8; _j++) {                                           \
      float4 _q = _rp[_j];                                                     \
      _in = __builtin_fmaf(xv[4*_j+0], _q.x, _in);                             \
      _in = __builtin_fmaf(xv[4*_j+1], _q.y, _in);                             \
      _in = __builtin_fmaf(xv[4*_j+2], _q.z, _in);                             \
      _in = __builtin_fmaf(xv[4*_j+3], _q.w, _in);                             \
    }                                                                          \
    float _d = (x2 + s_c2h[_kl]) - 2.0f * _in;                                 \
    float _L = plog_xla(_d);                                                   \
    uint32_t _v0, _v1;                                                         \
    threefry2x32(0u, 42u, 0u, lbase + (uint32_t)_kl, _v0, _v1);                \
    OUT = gumbel_from_bits(_v0 ^ _v1) + _L;                                    \
  }

// two k per expansion: rows from GLOBAL, wave-uniform addr (one line/wave)
#define GROUP2(KL, LA, LB)                                                     \
  {                                                                            \
    const int kl = kc + (KL);                                                  \
    const float2 c2p = *(const float2*)(s_c2h + kl);                           \
    const float4* r0 = (const float4*)(cbm + (size_t)kl * DD);                 \
    const float4* r1 = r0 + 8;                                                 \
    float i0 = 0.0f, i1 = 0.0f;                                                \
    _Pragma("unroll")                                                          \
    for (int j = 0; j < 8; j++) {                                              \
      float4 q0 = r0[j], q1 = r1[j];                                           \
      i0 = __builtin_fmaf(xv[4*j+0], q0.x, i0);                                \
      i1 = __builtin_fmaf(xv[4*j+0], q1.x, i1);                                \
      i0 = __builtin_fmaf(xv[4*j+1], q0.y, i0);                                \
      i1 = __builtin_fmaf(xv[4*j+1], q1.y, i1);                                \
      i0 = __builtin_fmaf(xv[4*j+2], q0.z, i0);                                \
      i1 = __builtin_fmaf(xv[4*j+2], q1.z, i1);                                \
      i0 = __builtin_fmaf(xv[4*j+3], q0.w, i0);                                \
      i1 = __builtin_fmaf(xv[4*j+3], q1.w, i1);                                \
    }                                                                          \
    float d0 = (x2 + c2p.x) - 2.0f * i0;                                       \
    float d1 = (x2 + c2p.y) - 2.0f * i1;                                       \
    LA = __log2f(d0) * LN2F;                                                   \
    LB = __log2f(d1) * LN2F;                                                   \
    uint32_t a0, a1, b0, b1;                                                   \
    threefry2x32(0u, 42u, 0u, lbase + (uint32_t)kl,        a0, a1);            \
    threefry2x32(0u, 42u, 0u, lbase + (uint32_t)(kl + 1),  b0, b1);            \
    float pA = gumbel_fast(a0 ^ a1) + LA;                                      \
    float pB = gumbel_fast(b0 ^ b1) + LB;                                      \
    TRACK(pA, kl,     best, sec, thi, bi1, bi2)                                \
    TRACK(pB, kl + 1, best, sec, thi, bi1, bi2)                                \
  }

__global__ __launch_bounds__(256, 8)
void mcq_main(const float* __restrict__ x, const float* __restrict__ cb,
              float* __restrict__ logit, uint2* __restrict__ ws) {
  __shared__ __align__(16) float s_c2h[HALF];       // 512 B (only LDS use)

  const int t   = threadIdx.x;
  const int bid = blockIdx.x;          // 2048 blocks = (group g, half h)
  const int g   = bid >> 1;
  const int h   = bid & 1;
  const int nm  = g >> 4;
  const int m   = nm & 3;
  const int hw  = ((g & 15) << 8) + t;
  const int gp  = (nm << 12) + hw;     // global pixel

  const float* cbm = cb + (size_t)m * (KK * DD) + (size_t)h * (HALF * DD);

  // x[d] -> VGPRs (coalesced across threads per d)
  const float* xp = x + ((size_t)(nm * 32)) * 4096 + hw;
  float xv[DD];
  #pragma unroll
  for (int d = 0; d < DD; d++) xv[d] = xp[(size_t)d * 4096];

  const float x2 = sumsq_unfused(xv);

  // c2 for local rows 0..127 (validated unfused chain), from global
  if (t < HALF) {
    const float4* rp = (const float4*)(cbm + t * DD);
    float cr[DD];
    #pragma unroll
    for (int j = 0; j < 8; j++) {
      float4 q = rp[j];
      cr[4*j+0] = q.x; cr[4*j+1] = q.y; cr[4*j+2] = q.z; cr[4*j+3] = q.w;
    }
    s_c2h[t] = sumsq_unfused(cr);
  }
  __syncthreads();

  float* lrow = logit + ((size_t)gp << 8) + h * HALF;
  const uint32_t lbase = ((uint32_t)gp << 8) + (uint32_t)(h * HALF);

  float best = -__builtin_inff(), sec = -__builtin_inff(), thi = -__builtin_inff();
  int bi1 = 0, bi2 = 0;

  #pragma unroll 1
  for (int kc = 0; kc < HALF; kc += 8) {
    float L0, L1, L2, L3, L4, L5, L6, L7;   // named regs only
    GROUP2(0, L0, L1)
    GROUP2(2, L2, L3)
    GROUP2(4, L4, L5)
    GROUP2(6, L6, L7)
    float4* dst = (float4*)(lrow + kc);     // 32B bursts
    dst[0] = make_float4(L0, L1, L2, L3);
    dst[1] = make_float4(L4, L5, L6, L7);
  }

  // resolve half-winner with exact phi (validated R10 logic)
  int wbl; float fw;
  if (best - sec > MARGIN) {
    wbl = bi1;
    EXACT_PHI(fw, wbl)
  } else if (best - thi > MARGIN) {
    int ka = bi1 < bi2 ? bi1 : bi2;
    int kb = bi1 < bi2 ? bi2 : bi1;
    float fa, fb;
    EXACT_PHI(fa, ka)
    EXACT_PHI(fb, kb)
    if (fb > fa) { wbl = kb; fw = fb; } else { wbl = ka; fw = fa; }
  } else {
    // ultra-rare: full exact scan of this half
    float bb = -__builtin_inff(); int wbb = 0;
    for (int kl = 0; kl < HALF; kl++) {
      float ph;
      EXACT_PHI(ph, kl)
      if (ph > bb) { bb = ph; wbb = kl; }
    }
    wbl = wbb; fw = bb;
  }

  ws[(h << 18) + gp] = make_uint2(__float_as_uint(fw), (uint32_t)(wbl + h * HALF));
}

__global__ __launch_bounds__(256)
void mcq_combine(const uint2* __restrict__ ws, float* __restrict__ sample,
                 float* __restrict__ code) {
  __shared__ int s_wb[256];
  const int t = threadIdx.x;
  const int b = blockIdx.x;          // 1024 blocks x 256 pixels
  const int gp = (b << 8) + t;

  uint2 a = ws[gp];
  uint2 c = ws[P_TOT + gp];
  float fa = __uint_as_float(a.x);
  float fc = __uint_as_float(c.x);
  // exact compare; tie -> half 0 (smaller k, first occurrence)
  int win = (fc > fa) ? (int)c.y : (int)a.y;

  code[gp] = (float)win;
  s_wb[t] = win;
  __syncthreads();

  const int lane = t & 63, wv = t >> 6;
  const int pbase = b << 8;
  const int k0 = lane << 2;
  for (int r = wv * 64; r < (wv + 1) * 64; r++) {
    const int w = s_wb[r];
    float4 v;
    v.x = (w == k0 + 0) ? 1.0f : 0.0f;
    v.y = (w == k0 + 1) ? 1.0f : 0.0f;
    v.z = (w == k0 + 2) ? 1.0f : 0.0f;
    v.w = (w == k0 + 3) ? 1.0f : 0.0f;
    ((float4*)(sample + (((size_t)(pbase + r)) << 8)))[lane] = v;
  }
}

extern "C" void kernel_launch(void* const* d_in, const int* in_sizes, int n_in,
                              void* d_out, int out_size, void* d_ws, size_t ws_size,
                              hipStream_t stream) {
  const float* x  = (const float*)d_in[0];
  const float* cb = (const float*)d_in[1];

  float* out_f  = (float*)d_out;
  float* sample = out_f;                       // 67108864
  float* code   = out_f + 67108864;            // 262144 (as float)
  float* logit  = out_f + 67108864 + 262144;   // 67108864
  uint2* ws     = (uint2*)d_ws;                // 2 * 262144 * 8B = 4 MB

  mcq_main<<<2048, 256, 0, stream>>>(x, cb, logit, ws);
  mcq_combine<<<1024, 256, 0, stream>>>(ws, sample, code);
}